// Round 2
// baseline (369.079 us; speedup 1.0000x reference)
//
#include <hip/hip_runtime.h>
#include <math.h>

constexpr int N = 100000;
constexpr int E = 1600000;
constexpr int C = 128;
constexpr int NPB   = 256;                       // nodes per bucket (pow2 -> shifts)
constexpr int NBUCK = (N + NPB - 1) / NPB;       // 391 buckets
constexpr int CAP   = 9472;                      // staging cap/bucket (mean 8192, +14 sigma)

__device__ inline unsigned f2bf(float f) {   // fp32 -> bf16 bits, RNE
    unsigned u = __float_as_uint(f);
    return (u + 0x7fffu + ((u >> 16) & 1u)) >> 16;
}
__device__ inline unsigned pack2(float lo, float hi) {
    return f2bf(lo) | (f2bf(hi) << 16);
}
__device__ inline float bf_lo(unsigned m) { return __uint_as_float(m << 16); }
__device__ inline float bf_hi(unsigned m) { return __uint_as_float(m & 0xffff0000u); }

// ------------------------------------------------------------- bin pass ----
__global__ __launch_bounds__(256) void k_bin(const int* __restrict__ ei,
                                             int* __restrict__ gcount,
                                             unsigned* __restrict__ staging) {
    __shared__ int cnt[NBUCK];
    __shared__ int wbase[NBUCK];
    const int t = threadIdx.x;
    const long tile = (long)blockIdx.x * 2048;
    for (int i = t; i < NBUCK; i += 256) cnt[i] = 0;
    __syncthreads();
    int b0[8], b1[8], lo0[8], lo1[8];
    unsigned p0[8], p1[8];
    bool val[8];
#pragma unroll
    for (int j = 0; j < 8; ++j) {
        long e = tile + j * 256 + t;
        val[j] = e < E;
        if (val[j]) {
            int u = __builtin_nontemporal_load(ei + e);
            int v = __builtin_nontemporal_load(ei + E + e);
            b0[j] = u >> 8;
            b1[j] = v >> 8;
            p0[j] = ((unsigned)(u & 255) << 17) | (unsigned)v;
            p1[j] = ((unsigned)(v & 255) << 17) | (unsigned)u;
            lo0[j] = atomicAdd(&cnt[b0[j]], 1);
            lo1[j] = atomicAdd(&cnt[b1[j]], 1);
        }
    }
    __syncthreads();
    for (int i = t; i < NBUCK; i += 256) wbase[i] = atomicAdd(&gcount[i], cnt[i]);
    __syncthreads();
#pragma unroll
    for (int j = 0; j < 8; ++j) {
        if (val[j]) {
            staging[(size_t)b0[j] * CAP + wbase[b0[j]] + lo0[j]] = p0[j];
            staging[(size_t)b1[j] * CAP + wbase[b1[j]] + lo1[j]] = p1[j];
        }
    }
}

// -------------------------------------------------- per-bucket CSR build ---
__global__ __launch_bounds__(512) void k_csr(const unsigned* __restrict__ staging,
                                             const int* __restrict__ gcount,
                                             int* __restrict__ deg,
                                             float* __restrict__ dinv,
                                             int* __restrict__ rowptr,
                                             int* __restrict__ adj) {
    __shared__ int hist[NPB + 1];
    __shared__ int wpart[8];
    __shared__ int wsum[8];
    __shared__ int sh_base;
    const int g = blockIdx.x;
    const int t = threadIdx.x;
    const int lane = t & 63, wid = t >> 6;
    const int cnt = gcount[g];
    // block-parallel prefix: base = sum gcount[0..g)
    int s = (t < g) ? gcount[t] : 0;
#pragma unroll
    for (int off = 32; off; off >>= 1) s += __shfl_down(s, off);
    if (lane == 0) wsum[wid] = s;
    for (int i = t; i <= NPB; i += 512) hist[i] = 0;
    __syncthreads();
    if (t == 0) {
        int r = 0;
#pragma unroll
        for (int w = 0; w < 8; ++w) r += wsum[w];
        sh_base = r;
    }
    const unsigned* base = staging + (size_t)g * CAP;
    for (int i = t; i < cnt; i += 512) atomicAdd(&hist[base[i] >> 17], 1);
    __syncthreads();
    const int a = (t < NPB) ? hist[t] : 0;
    int v = a;
#pragma unroll
    for (int off = 1; off < 64; off <<= 1) {
        int n = __shfl_up(v, off);
        if (lane >= off) v += n;
    }
    if (lane == 63 && wid < NPB / 64) wpart[wid] = v;
    __syncthreads();
    if (t == 0) {
        int r = 0;
#pragma unroll
        for (int w = 0; w < NPB / 64; ++w) { int x = wpart[w]; wpart[w] = r; r += x; }
    }
    __syncthreads();
    if (t < NPB) hist[t] = v - a + wpart[wid];
    if (t == 0) hist[NPB] = cnt;
    __syncthreads();
    const int nbase = g * NPB;
    const int nlocal = min(NPB, N - nbase);
    const int bbase = sh_base;
    if (t < nlocal) {
        const int st = hist[t], en = hist[t + 1];
        const int d = en - st;
        deg[nbase + t] = d;
        dinv[nbase + t] = rsqrtf((float)d + 1.0f);
        rowptr[nbase + t] = bbase + st;
    }
    __syncthreads();
    int* aslice = adj + bbase;
    for (int i = t; i < cnt; i += 512) {
        const unsigned e = base[i];
        const int pos = atomicAdd(&hist[e >> 17], 1);
        aslice[pos] = (int)(e & 0x1ffffu);
    }
}

// ------------------------------------------------------------------ GEMM ---
// z16 = bf16(dinv[row] * (x @ W)).
__global__ __launch_bounds__(256) void k_gemm(const float* __restrict__ x,
                                              const float* __restrict__ W,
                                              const float* __restrict__ dinv,
                                              unsigned* __restrict__ z16) {
    __shared__ float Ws[32][128];
    __shared__ float xs[64][33];

    const int t   = threadIdx.x;
    const int r0  = (t & 15) * 4;
    const int c0  = (t >> 4) * 8;
    const int bid = blockIdx.x;

    float acc[4][8];
#pragma unroll
    for (int i = 0; i < 4; ++i)
#pragma unroll
        for (int j = 0; j < 8; ++j) acc[i][j] = 0.0f;

    const int lrow = t >> 2;
    const int lk   = (t & 3) * 8;
    const long grow = (long)bid * 64 + lrow;
    const bool rvalid = grow < N;

    for (int k0 = 0; k0 < C; k0 += 32) {
        const float4* Wg = (const float4*)(W + (size_t)k0 * C);
        float4* Wsv = (float4*)(&Ws[0][0]);
#pragma unroll
        for (int j = 0; j < 4; ++j) Wsv[t + 256 * j] = Wg[t + 256 * j];
        float4 a0 = {0, 0, 0, 0}, a1 = {0, 0, 0, 0};
        if (rvalid) {
            a0 = *(const float4*)(x + grow * C + k0 + lk);
            a1 = *(const float4*)(x + grow * C + k0 + lk + 4);
        }
        xs[lrow][lk + 0] = a0.x; xs[lrow][lk + 1] = a0.y;
        xs[lrow][lk + 2] = a0.z; xs[lrow][lk + 3] = a0.w;
        xs[lrow][lk + 4] = a1.x; xs[lrow][lk + 5] = a1.y;
        xs[lrow][lk + 6] = a1.z; xs[lrow][lk + 7] = a1.w;
        __syncthreads();

#pragma unroll 8
        for (int k = 0; k < 32; ++k) {
            float4 w0 = *(const float4*)&Ws[k][c0];
            float4 w1 = *(const float4*)&Ws[k][c0 + 4];
            float xv[4];
#pragma unroll
            for (int i = 0; i < 4; ++i) xv[i] = xs[r0 + i][k];
#pragma unroll
            for (int i = 0; i < 4; ++i) {
                acc[i][0] = fmaf(xv[i], w0.x, acc[i][0]);
                acc[i][1] = fmaf(xv[i], w0.y, acc[i][1]);
                acc[i][2] = fmaf(xv[i], w0.z, acc[i][2]);
                acc[i][3] = fmaf(xv[i], w0.w, acc[i][3]);
                acc[i][4] = fmaf(xv[i], w1.x, acc[i][4]);
                acc[i][5] = fmaf(xv[i], w1.y, acc[i][5]);
                acc[i][6] = fmaf(xv[i], w1.z, acc[i][6]);
                acc[i][7] = fmaf(xv[i], w1.w, acc[i][7]);
            }
        }
        __syncthreads();
    }

#pragma unroll
    for (int i = 0; i < 4; ++i) {
        long r = (long)bid * 64 + r0 + i;
        if (r >= N) break;
        const float dv = dinv[r];
        uint4 pk = {pack2(dv * acc[i][0], dv * acc[i][1]), pack2(dv * acc[i][2], dv * acc[i][3]),
                    pack2(dv * acc[i][4], dv * acc[i][5]), pack2(dv * acc[i][6], dv * acc[i][7])};
        *(uint4*)(z16 + r * (C / 2) + (c0 >> 1)) = pk;
    }
}

// ---------------------------------------------------------------- gather ---
// One wave per node. 4x memory-level parallelism: lanes split into 4
// quadrants of 16; quadrant q loads 16 B (dwordx4) of row v[4g+q], so one
// wave-load covers 4 edges / 16 cachelines (vs 1 edge / 4 lines before).
// Full 64-edge chunks run a software-pipelined fast path with 8 wave-loads
// (32 edges / 128 lines) in flight. Lane owns channels 8*(lane&15)..+7 for
// its quadrant's rows; shfl_xor(16/32) butterfly merges quadrants per node.
__global__ __launch_bounds__(256) void k_gather(const int* __restrict__ rowptr,
                                                const int* __restrict__ deg,
                                                const float* __restrict__ dinv,
                                                const int* __restrict__ adj,
                                                const unsigned* __restrict__ z16,
                                                const float* __restrict__ b,
                                                float* __restrict__ out) {
    const int u = blockIdx.x * 4 + (threadIdx.x >> 6);
    if (u >= N) return;
    const int lane = threadIdx.x & 63;
    const int q    = lane >> 4;      // quadrant (row within group of 4 edges)
    const int c    = lane & 15;      // column group: dwords 4c..4c+3 of a row
    const int d  = __builtin_amdgcn_readfirstlane(deg[u]);
    const int st = __builtin_amdgcn_readfirstlane(rowptr[u]);
    const float du = dinv[u];

    float acc[8];
#pragma unroll
    for (int i = 0; i < 8; ++i) acc[i] = 0.f;

#define LDG(g) (*(const uint4*)(z16 + (((size_t)(unsigned)__shfl(v, 4 * (g) + q)) << 6) + 4 * c))
#define ACC(m)                                            \
    {                                                     \
        acc[0] += bf_lo((m).x); acc[1] += bf_hi((m).x);   \
        acc[2] += bf_lo((m).y); acc[3] += bf_hi((m).y);   \
        acc[4] += bf_lo((m).z); acc[5] += bf_hi((m).z);   \
        acc[6] += bf_lo((m).w); acc[7] += bf_hi((m).w);   \
    }

    // self-loop: quadrant 0 only (counted once after butterfly)
    if (q == 0) {
        uint4 m = *(const uint4*)(z16 + ((size_t)(unsigned)u << 6) + 4 * c);
        ACC(m);
    }

    for (int j0 = 0; j0 < d; j0 += 64) {
        const int cntc = min(64, d - j0);
        int v = 0;
        if (lane < cntc) v = adj[st + j0 + lane];
        if (cntc == 64) {
            // fast path: 16 groups of 4 edges, 8 wave-loads in flight
            uint4 m0 = LDG(0), m1 = LDG(1), m2 = LDG(2), m3 = LDG(3);
            uint4 m4 = LDG(4), m5 = LDG(5), m6 = LDG(6), m7 = LDG(7);
            uint4 n0 = LDG(8);  ACC(m0);
            uint4 n1 = LDG(9);  ACC(m1);
            uint4 n2 = LDG(10); ACC(m2);
            uint4 n3 = LDG(11); ACC(m3);
            uint4 n4 = LDG(12); ACC(m4);
            uint4 n5 = LDG(13); ACC(m5);
            uint4 n6 = LDG(14); ACC(m6);
            uint4 n7 = LDG(15); ACC(m7);
            ACC(n0); ACC(n1); ACC(n2); ACC(n3);
            ACC(n4); ACC(n5); ACC(n6); ACC(n7);
        } else {
            const int ng = (cntc + 3) >> 2;
            for (int g = 0; g < ng; ++g) {
                const int e = 4 * g + q;
                const int vq = __shfl(v, e);
                if (e < cntc) {
                    uint4 m = *(const uint4*)(z16 + (((size_t)(unsigned)vq) << 6) + 4 * c);
                    ACC(m);
                }
            }
        }
    }
#undef LDG
#undef ACC

    // merge the 4 quadrant partials: lanes l, l^16, l^32, l^48 hold the same
    // 8 channels for disjoint edge subsets
#pragma unroll
    for (int i = 0; i < 8; ++i) {
        acc[i] += __shfl_xor(acc[i], 16);
        acc[i] += __shfl_xor(acc[i], 32);
    }

    if (q == 0) {
        const float4 b0 = *(const float4*)(b + 8 * c);
        const float4 b1 = *(const float4*)(b + 8 * c + 4);
        float4 o0, o1;
        o0.x = fmaf(du, acc[0], b0.x); o0.y = fmaf(du, acc[1], b0.y);
        o0.z = fmaf(du, acc[2], b0.z); o0.w = fmaf(du, acc[3], b0.w);
        o1.x = fmaf(du, acc[4], b1.x); o1.y = fmaf(du, acc[5], b1.y);
        o1.z = fmaf(du, acc[6], b1.z); o1.w = fmaf(du, acc[7], b1.w);
        *(float4*)(out + (size_t)u * C + 8 * c)     = o0;
        *(float4*)(out + (size_t)u * C + 8 * c + 4) = o1;
    }
}

// ---------------------------------------------------------------- launch ---
extern "C" void kernel_launch(void* const* d_in, const int* in_sizes, int n_in,
                              void* d_out, int out_size, void* d_ws, size_t ws_size,
                              hipStream_t stream) {
    const float* x  = (const float*)d_in[0];
    const float* W  = (const float*)d_in[1];
    const float* b  = (const float*)d_in[2];
    const int*   ei = (const int*)d_in[3];
    float* out = (float*)d_out;

    // workspace: z16 [N*64 u32] | deg [N] | dinv [N] | rowptr [N+4] |
    //            gcount [512] | staging [NBUCK*CAP u32] | adj [2E]
    char* p = (char*)d_ws;
    unsigned* z16 = (unsigned*)p;   p += (size_t)N * (C / 2) * sizeof(unsigned);
    int* deg = (int*)p;             p += (size_t)N * sizeof(int);
    float* dinv = (float*)p;        p += (size_t)N * sizeof(float);
    int* rowptr = (int*)p;          p += (size_t)(N + 4) * sizeof(int);
    int* gcount = (int*)p;          p += 512 * sizeof(int);
    unsigned* staging = (unsigned*)p; p += (size_t)NBUCK * CAP * sizeof(unsigned);
    int* adj = (int*)p;

    hipMemsetAsync(gcount, 0, 512 * sizeof(int), stream);
    k_bin<<<(E + 2047) / 2048, 256, 0, stream>>>(ei, gcount, staging);
    k_csr<<<NBUCK, 512, 0, stream>>>(staging, gcount, deg, dinv, rowptr, adj);
    k_gemm<<<(N + 63) / 64, 256, 0, stream>>>(x, W, dinv, z16);
    k_gather<<<(N + 3) / 4, 256, 0, stream>>>(rowptr, deg, dinv, adj, z16, b, out);
}

// Round 3
// 333.121 us; speedup vs baseline: 1.1079x; 1.1079x over previous
//
#include <hip/hip_runtime.h>
#include <math.h>

constexpr int N = 100000;
constexpr int E = 1600000;
constexpr int C = 128;
constexpr int NPB   = 256;                       // nodes per bucket (pow2 -> shifts)
constexpr int NBUCK = (N + NPB - 1) / NPB;       // 391 buckets
constexpr int CAP   = 9472;                      // staging cap/bucket (mean 8192, +14 sigma)
constexpr int ADJ_STRIDE = CAP + NPB * 7;        // 11264: padded adj slots per bucket

__device__ inline unsigned f2bf(float f) {   // fp32 -> bf16 bits, RNE
    unsigned u = __float_as_uint(f);
    return (u + 0x7fffu + ((u >> 16) & 1u)) >> 16;
}
__device__ inline unsigned pack2(float lo, float hi) {
    return f2bf(lo) | (f2bf(hi) << 16);
}
__device__ inline float bf_lo(unsigned m) { return __uint_as_float(m << 16); }
__device__ inline float bf_hi(unsigned m) { return __uint_as_float(m & 0xffff0000u); }

// ------------------------------------------------------------- bin pass ----
__global__ __launch_bounds__(256) void k_bin(const int* __restrict__ ei,
                                             int* __restrict__ gcount,
                                             unsigned* __restrict__ staging) {
    __shared__ int cnt[NBUCK];
    __shared__ int wbase[NBUCK];
    const int t = threadIdx.x;
    const long tile = (long)blockIdx.x * 2048;
    for (int i = t; i < NBUCK; i += 256) cnt[i] = 0;
    __syncthreads();
    int b0[8], b1[8], lo0[8], lo1[8];
    unsigned p0[8], p1[8];
    bool val[8];
#pragma unroll
    for (int j = 0; j < 8; ++j) {
        long e = tile + j * 256 + t;
        val[j] = e < E;
        if (val[j]) {
            int u = __builtin_nontemporal_load(ei + e);
            int v = __builtin_nontemporal_load(ei + E + e);
            b0[j] = u >> 8;
            b1[j] = v >> 8;
            p0[j] = ((unsigned)(u & 255) << 17) | (unsigned)v;
            p1[j] = ((unsigned)(v & 255) << 17) | (unsigned)u;
            lo0[j] = atomicAdd(&cnt[b0[j]], 1);
            lo1[j] = atomicAdd(&cnt[b1[j]], 1);
        }
    }
    __syncthreads();
    for (int i = t; i < NBUCK; i += 256) wbase[i] = atomicAdd(&gcount[i], cnt[i]);
    __syncthreads();
#pragma unroll
    for (int j = 0; j < 8; ++j) {
        if (val[j]) {
            staging[(size_t)b0[j] * CAP + wbase[b0[j]] + lo0[j]] = p0[j];
            staging[(size_t)b1[j] * CAP + wbase[b1[j]] + lo1[j]] = p1[j];
        }
    }
}

// -------------------------------------------------- per-bucket CSR build ---
// Fixed per-bucket adj stride (no cross-bucket prefix needed). Per-node
// adjacency rows padded to a multiple of 8 with dummy id = N (points at a
// zeroed z-row) so the gather inner loop needs no tail guards.
__global__ __launch_bounds__(512) void k_csr(const unsigned* __restrict__ staging,
                                             const int* __restrict__ gcount,
                                             int* __restrict__ deg,
                                             float* __restrict__ dinv,
                                             int* __restrict__ rowptr,
                                             int* __restrict__ adj) {
    __shared__ int hist[NPB];
    __shared__ int wpart[4];
    const int g = blockIdx.x;
    const int t = threadIdx.x;
    const int lane = t & 63, wid = t >> 6;
    const int cnt = gcount[g];
    int* slice = adj + (size_t)g * ADJ_STRIDE;
    // prefill slice with dummy id N (zero row); scatter overwrites real slots
    {
        const int4 fill = {N, N, N, N};
        for (int i = t; i < ADJ_STRIDE / 4; i += 512) ((int4*)slice)[i] = fill;
    }
    for (int i = t; i < NPB; i += 512) hist[i] = 0;
    __syncthreads();
    const unsigned* base = staging + (size_t)g * CAP;
    // pass 1: histogram of local dest ids
    for (int i = t; i < cnt; i += 512) atomicAdd(&hist[base[i] >> 17], 1);
    __syncthreads();
    // exclusive scan of PADDED degrees (pad-to-8)
    const int d  = (t < NPB) ? hist[t] : 0;
    const int pd = (d + 7) & ~7;
    int v = pd;
#pragma unroll
    for (int off = 1; off < 64; off <<= 1) {
        int n = __shfl_up(v, off);
        if (lane >= off) v += n;
    }
    if (lane == 63 && wid < 4) wpart[wid] = v;
    __syncthreads();
    if (t == 0) {
        int r = 0;
#pragma unroll
        for (int w = 0; w < 4; ++w) { int x = wpart[w]; wpart[w] = r; r += x; }
    }
    __syncthreads();
    const int pstart = v - pd + ((wid < 4) ? wpart[wid] : 0);
    if (t < NPB) {
        const int node = g * NPB + t;
        if (node < N) {
            deg[node]    = d;
            dinv[node]   = rsqrtf((float)d + 1.0f);
            rowptr[node] = g * ADJ_STRIDE + pstart;
        }
    }
    __syncthreads();
    if (t < NPB) hist[t] = pstart;   // cursor for pass 2
    __syncthreads();
    // pass 2: fill adj via LDS cursors
    for (int i = t; i < cnt; i += 512) {
        const unsigned e = base[i];
        const int pos = atomicAdd(&hist[e >> 17], 1);
        slice[pos] = (int)(e & 0x1ffffu);
    }
}

// ------------------------------------------------------------------ GEMM ---
// z = bf16(dinv[row] * (x @ W)), split into two half-channel arrays:
// z_lo = channels 0..63, z_hi = channels 64..127 (each row 32 u32 = 128 B).
__global__ __launch_bounds__(256) void k_gemm(const float* __restrict__ x,
                                              const float* __restrict__ W,
                                              const float* __restrict__ dinv,
                                              unsigned* __restrict__ z_lo,
                                              unsigned* __restrict__ z_hi) {
    __shared__ float Ws[32][128];
    __shared__ float xs[64][33];

    const int t   = threadIdx.x;
    const int r0  = (t & 15) * 4;
    const int c0  = (t >> 4) * 8;
    const int bid = blockIdx.x;

    float acc[4][8];
#pragma unroll
    for (int i = 0; i < 4; ++i)
#pragma unroll
        for (int j = 0; j < 8; ++j) acc[i][j] = 0.0f;

    const int lrow = t >> 2;
    const int lk   = (t & 3) * 8;
    const long grow = (long)bid * 64 + lrow;
    const bool rvalid = grow < N;

    for (int k0 = 0; k0 < C; k0 += 32) {
        const float4* Wg = (const float4*)(W + (size_t)k0 * C);
        float4* Wsv = (float4*)(&Ws[0][0]);
#pragma unroll
        for (int j = 0; j < 4; ++j) Wsv[t + 256 * j] = Wg[t + 256 * j];
        float4 a0 = {0, 0, 0, 0}, a1 = {0, 0, 0, 0};
        if (rvalid) {
            a0 = *(const float4*)(x + grow * C + k0 + lk);
            a1 = *(const float4*)(x + grow * C + k0 + lk + 4);
        }
        xs[lrow][lk + 0] = a0.x; xs[lrow][lk + 1] = a0.y;
        xs[lrow][lk + 2] = a0.z; xs[lrow][lk + 3] = a0.w;
        xs[lrow][lk + 4] = a1.x; xs[lrow][lk + 5] = a1.y;
        xs[lrow][lk + 6] = a1.z; xs[lrow][lk + 7] = a1.w;
        __syncthreads();

#pragma unroll 8
        for (int k = 0; k < 32; ++k) {
            float4 w0 = *(const float4*)&Ws[k][c0];
            float4 w1 = *(const float4*)&Ws[k][c0 + 4];
            float xv[4];
#pragma unroll
            for (int i = 0; i < 4; ++i) xv[i] = xs[r0 + i][k];
#pragma unroll
            for (int i = 0; i < 4; ++i) {
                acc[i][0] = fmaf(xv[i], w0.x, acc[i][0]);
                acc[i][1] = fmaf(xv[i], w0.y, acc[i][1]);
                acc[i][2] = fmaf(xv[i], w0.z, acc[i][2]);
                acc[i][3] = fmaf(xv[i], w0.w, acc[i][3]);
                acc[i][4] = fmaf(xv[i], w1.x, acc[i][4]);
                acc[i][5] = fmaf(xv[i], w1.y, acc[i][5]);
                acc[i][6] = fmaf(xv[i], w1.z, acc[i][6]);
                acc[i][7] = fmaf(xv[i], w1.w, acc[i][7]);
            }
        }
        __syncthreads();
    }

    unsigned* zh = (c0 < 64) ? z_lo : z_hi;
    const int ch = (c0 & 63) >> 1;
#pragma unroll
    for (int i = 0; i < 4; ++i) {
        long r = (long)bid * 64 + r0 + i;
        if (r >= N) break;
        const float dv = dinv[r];
        uint4 pk = {pack2(dv * acc[i][0], dv * acc[i][1]), pack2(dv * acc[i][2], dv * acc[i][3]),
                    pack2(dv * acc[i][4], dv * acc[i][5]), pack2(dv * acc[i][6], dv * acc[i][7])};
        *(uint4*)(zh + r * 32 + ch) = pk;
    }
}

// ---------------------------------------------------------------- gather ---
// Two sequential half-channel passes in one dispatch (blocks [0,NB_H) do
// channels 0..63 from z_lo; blocks [NB_H,2*NB_H) do 64..127 from z_hi) --
// halves the random-gather working set per time window (25.6 -> 12.8 MB) to
// raise L2 hit rate. One wave per node; half-row = 128 B, so one wave-load
// covers a PAIR of edges (lanes 0-31 -> edge 2p, lanes 32-63 -> edge 2p+1).
// Adjacency rows are padded to x8 with dummy id N (zero row): no tail
// guards, ping-pong pipeline keeps 8 loads (16 edges) in flight.
__global__ __launch_bounds__(256) void k_gather(const int* __restrict__ rowptr,
                                                const int* __restrict__ deg,
                                                const float* __restrict__ dinv,
                                                const int* __restrict__ adj,
                                                const unsigned* __restrict__ z_lo,
                                                const unsigned* __restrict__ z_hi,
                                                const float* __restrict__ b,
                                                float* __restrict__ out,
                                                int nb_h) {
    const int half = (blockIdx.x >= nb_h) ? 1 : 0;
    const int u = (blockIdx.x - half * nb_h) * 4 + (threadIdx.x >> 6);
    if (u >= N) return;
    const int lane = threadIdx.x & 63;
    const int h = lane >> 5;          // which edge of the pair
    const int c = lane & 31;          // u32 index within the 128 B half-row
    const int d  = __builtin_amdgcn_readfirstlane(deg[u]);
    const int pd = (d + 7) & ~7;
    const int st = __builtin_amdgcn_readfirstlane(rowptr[u]);
    const float du = dinv[u];
    const unsigned* zh = (half ? z_hi : z_lo) + c;

    // self-loop on the h==0 side only (merged once by the final shfl_xor)
    float ax, ay;
    {
        const unsigned ms = (h == 0) ? zh[(size_t)(unsigned)u << 5] : 0u;
        ax = bf_lo(ms); ay = bf_hi(ms);
    }

#define RL(i) __builtin_amdgcn_readlane(v, (i))
#define LDP(P) (zh[(size_t)(unsigned)(h ? RL(2 * (P) + 1) : RL(2 * (P))) << 5])
#define ACC(m) { ax += bf_lo(m); ay += bf_hi(m); }

    for (int j0 = 0; j0 < pd; j0 += 64) {
        const int cntc = min(64, pd - j0);    // multiple of 8, wave-uniform
        int v = 0;
        if (lane < cntc) v = adj[st + j0 + lane];
        const int np = cntc >> 1;             // pairs: 4..32, multiple of 4
        unsigned m0 = LDP(0), m1 = LDP(1), m2 = LDP(2), m3 = LDP(3);
        for (int p = 4; p < np; p += 4) {
            unsigned n0 = LDP(p), n1 = LDP(p + 1), n2 = LDP(p + 2), n3 = LDP(p + 3);
            ACC(m0); ACC(m1); ACC(m2); ACC(m3);
            m0 = n0; m1 = n1; m2 = n2; m3 = n3;
        }
        ACC(m0); ACC(m1); ACC(m2); ACC(m3);
    }
#undef RL
#undef LDP
#undef ACC

    // merge even/odd-edge partials: lanes l and l^32 hold the same channels
    ax += __shfl_xor(ax, 32);
    ay += __shfl_xor(ay, 32);

    if (h == 0) {
        const float* bh = b + 64 * half + 2 * c;
        const float2 bb = {bh[0], bh[1]};
        float2 o = {fmaf(du, ax, bb.x), fmaf(du, ay, bb.y)};
        *(float2*)(out + (size_t)u * C + 64 * half + 2 * c) = o;
    }
}

// ---------------------------------------------------------------- launch ---
extern "C" void kernel_launch(void* const* d_in, const int* in_sizes, int n_in,
                              void* d_out, int out_size, void* d_ws, size_t ws_size,
                              hipStream_t stream) {
    const float* x  = (const float*)d_in[0];
    const float* W  = (const float*)d_in[1];
    const float* b  = (const float*)d_in[2];
    const int*   ei = (const int*)d_in[3];
    float* out = (float*)d_out;

    // workspace (z overlays the dead staging region; staging consumed by
    // k_csr before k_gemm writes z):
    //   A [2*(N+1)*32 u32 = 25.6 MB] = staging [NBUCK*CAP u32 = 14.8 MB] / z_lo|z_hi
    //   adj [NBUCK*ADJ_STRIDE int = 17.6 MB] | deg | dinv | rowptr | gcount
    char* p = (char*)d_ws;
    unsigned* zbase = (unsigned*)p;
    unsigned* z_lo = zbase;
    unsigned* z_hi = zbase + (size_t)(N + 1) * 32;
    unsigned* staging = zbase;
    p += (size_t)2 * (N + 1) * 32 * sizeof(unsigned);
    int* adj = (int*)p;             p += (size_t)NBUCK * ADJ_STRIDE * sizeof(int);
    int* deg = (int*)p;             p += (size_t)N * sizeof(int);
    float* dinv = (float*)p;        p += (size_t)N * sizeof(float);
    int* rowptr = (int*)p;          p += (size_t)(N + 4) * sizeof(int);
    int* gcount = (int*)p;          p += 512 * sizeof(int);

    hipMemsetAsync(gcount, 0, 512 * sizeof(int), stream);
    k_bin<<<(E + 2047) / 2048, 256, 0, stream>>>(ei, gcount, staging);
    k_csr<<<NBUCK, 512, 0, stream>>>(staging, gcount, deg, dinv, rowptr, adj);
    // zero the dummy row N of each z half (staging is dead now)
    hipMemsetAsync(z_lo + (size_t)N * 32, 0, 128, stream);
    hipMemsetAsync(z_hi + (size_t)N * 32, 0, 128, stream);
    k_gemm<<<(N + 63) / 64, 256, 0, stream>>>(x, W, dinv, z_lo, z_hi);
    const int nb_h = (N + 3) / 4;
    k_gather<<<2 * nb_h, 256, 0, stream>>>(rowptr, deg, dinv, adj, z_lo, z_hi, b, out, nb_h);
}